// Round 7
// baseline (817.638 us; speedup 1.0000x reference)
//
#include <hip/hip_runtime.h>
#include <cstdint>

// Problem constants (fixed by reference: B=4, S=2048)
#define TOK  8192   // B*S
#define DEMB 1024   // N_EMBD
#define HID  4096   // HIDDEN
#define ADP  256    // ADAPT
#define NEXP 8
#define KAUG 4352   // HID + ADP (K-augmented out-proj)
#define NBLK 512    // persistent grid: 2 blocks/CU guaranteed co-resident (cap 768)

typedef __bf16 bf16x8 __attribute__((ext_vector_type(8)));
typedef float  f32x4  __attribute__((ext_vector_type(4)));

__device__ __forceinline__ unsigned short f2bf(float f) {
  // round-to-nearest-even fp32 -> bf16 (matches numpy/jax cast for normal values)
  unsigned int u = __float_as_uint(f);
  u += 0x7fffu + ((u >> 16) & 1u);
  return (unsigned short)(u >> 16);
}
__device__ __forceinline__ float bf2f(unsigned short b) {
  return __uint_as_float(((unsigned int)b) << 16);
}

// ---------------------------------------------------------------------------
// Device-scope grid barrier for the persistent kernel. Counter lives in d_ws
// (zeroed by hipMemsetAsync before launch). Release: __threadfence makes this
// block's global writes visible device-wide (cross-XCD) before signaling;
// acquire: fence after the spin invalidates stale L1/L2 lines before reads.
// Co-residency guaranteed: NBLK=512 <= 256 CUs x 3 blocks (launch_bounds cap).
// ---------------------------------------------------------------------------
__device__ __forceinline__ void grid_bar(int* bar, int target) {
  __syncthreads();
  if (threadIdx.x == 0) {
    __threadfence();
    __hip_atomic_fetch_add(bar, 1, __ATOMIC_ACQ_REL, __HIP_MEMORY_SCOPE_AGENT);
    while (__hip_atomic_load(bar, __ATOMIC_ACQUIRE, __HIP_MEMORY_SCOPE_AGENT) <
           target)
      __builtin_amdgcn_s_sleep(2);
    __threadfence();
  }
  __syncthreads();
}

// ---------------------------------------------------------------------------
// 128x128x(BK=64) bf16 MFMA GEMM body (m97 structure: global_load_lds w=16,
// XOR-swizzled LDS, 4 waves 2x2, 4x4 16x16x32 tiles/wave).
// EPI: 0 = silu -> bf16, 1 = fp32 store (+split-K offset),
//      3 = expert-select fp32 store (keep iff route[row] == col>>8).
// ---------------------------------------------------------------------------
__device__ __forceinline__ void stage_tile(const unsigned short* __restrict__ g,
                                           int ldg, unsigned short* lds,
                                           int wave, int lane) {
  int srow = lane >> 3;
  int scol = ((lane & 7) ^ (srow & 7)) * 8;
#pragma unroll
  for (int c = 0; c < 4; ++c) {
    int chunk = wave * 4 + c;
    const unsigned short* gp = g + (size_t)(chunk * 8 + srow) * ldg + scol;
    unsigned short* lp = lds + chunk * 512;
    __builtin_amdgcn_global_load_lds(
        (const __attribute__((address_space(1))) unsigned int*)(uintptr_t)gp,
        (__attribute__((address_space(3))) unsigned int*)(uintptr_t)lp,
        16, 0, 0);
  }
}

// XCD-aware remap: each XCD gets a contiguous band of gy/8 row-tiles with all
// col-tiles co-resident (requires gy % 8 == 0 and li&7 == xcd dispatch).
__device__ __forceinline__ void remap_xcd(int li, int gx, int gy,
                                          int& bx, int& by) {
  int xcd = li & 7;
  int slot = li >> 3;
  bx = slot % gx;
  by = xcd * (gy >> 3) + slot / gx;
}

template <int EPI>
__device__ __forceinline__ void gemm_body(
    int bxr, int byr, int bz,
    const unsigned short* __restrict__ A, int lda,
    const unsigned short* __restrict__ B, int ldb,
    void* __restrict__ C, int ldc,
    const int* __restrict__ route, int kLen, long splitStride,
    unsigned short* As, unsigned short* Bs) {
  const int lane = threadIdx.x & 63;
  const int wave = threadIdx.x >> 6;
  const int wm = wave >> 1, wn = wave & 1;
  const long rowBase = (long)byr * 128;
  const long colBase = (long)bxr * 128;
  const int ks = bz * kLen;
  const unsigned short* Ap = A + rowBase * lda + ks;
  const unsigned short* Bp = B + colBase * ldb + ks;
  f32x4 acc[4][4] = {};

  for (int kt = 0; kt < kLen; kt += 64) {
    stage_tile(Ap + kt, lda, As, wave, lane);
    stage_tile(Bp + kt, ldb, Bs, wave, lane);
    __syncthreads();
#pragma unroll
    for (int kk = 0; kk < 64; kk += 32) {
      const int kb = (kk >> 3) + (lane >> 4);   // k-block 0..7
      const int sw = kb ^ (lane & 7);           // swizzled k-block
      bf16x8 af[4], bfr[4];
#pragma unroll
      for (int mt = 0; mt < 4; ++mt) {
        int m = wm * 64 + mt * 16 + (lane & 15);
        af[mt] = *(const bf16x8*)&As[m * 64 + sw * 8];
      }
#pragma unroll
      for (int nt = 0; nt < 4; ++nt) {
        int n = wn * 64 + nt * 16 + (lane & 15);
        bfr[nt] = *(const bf16x8*)&Bs[n * 64 + sw * 8];
      }
#pragma unroll
      for (int mt = 0; mt < 4; ++mt)
#pragma unroll
        for (int nt = 0; nt < 4; ++nt)
          acc[mt][nt] = __builtin_amdgcn_mfma_f32_16x16x32_bf16(
              af[mt], bfr[nt], acc[mt][nt], 0, 0, 0);
    }
    __syncthreads();
  }

  // Epilogue. C/D layout (m89-verified): col = lane&15, row = (lane>>4)*4 + r.
  const int rsub = (lane >> 4) * 4;
  const int csub = lane & 15;
#pragma unroll
  for (int mt = 0; mt < 4; ++mt) {
#pragma unroll
    for (int nt = 0; nt < 4; ++nt) {
      long col = colBase + wn * 64 + nt * 16 + csub;
#pragma unroll
      for (int r = 0; r < 4; ++r) {
        long row = rowBase + wm * 64 + mt * 16 + rsub + r;
        float v = acc[mt][nt][r];
        if (EPI == 0) {
          float s = __fdividef(v, 1.0f + __expf(-v));  // silu
          ((unsigned short*)C)[row * ldc + col] = f2bf(s);
        } else if (EPI == 1) {
          ((float*)C + splitStride * bz)[row * ldc + col] = v;
        } else {  // EPI == 3: expert-select fp32 store into a_sel [TOK][ADP]
          if (route[row] == (int)(col >> 8))
            ((float*)C)[row * ADP + (col & 255)] = v;
        }
      }
    }
  }
}

// ---------------------------------------------------------------------------
// ONE persistent kernel: all 7 former launches as phases split by grid_bar.
// Eliminates ~6 dispatch boundaries (~10 us each observed r5->r6).
// Phase/tile maps keep block&7 == xcd owning the same row-bands throughout.
// ---------------------------------------------------------------------------
__global__ __launch_bounds__(256, 3) void fused_all(
    const float* __restrict__ x, const float* __restrict__ ew,
    const float* __restrict__ wup, const float* __restrict__ wadapt,
    const float* __restrict__ wexp, const float* __restrict__ gamma,
    const float* __restrict__ beta, const float* __restrict__ wp,
    const float* __restrict__ wout,
    unsigned short* __restrict__ xb, unsigned short* __restrict__ wub,
    unsigned short* __restrict__ wob, unsigned short* __restrict__ wab,
    unsigned short* __restrict__ web, unsigned short* __restrict__ wpT,
    unsigned short* __restrict__ Haug, float* __restrict__ P,
    float* __restrict__ Pw, unsigned short* __restrict__ ab,
    int* __restrict__ route, float* __restrict__ out, int* bar) {
  __shared__ unsigned char smem[32768];  // As+Bs for GEMM; aliased by transpose
  unsigned short* As = (unsigned short*)smem;
  unsigned short* Bs = (unsigned short*)(smem + 16384);
  const int b = blockIdx.x;
  const int xcd = b & 7, slot = b >> 3;   // slot in [0,64)
  const int tid = threadIdx.x;

  // ---- Phase A: fp32->bf16 converts + routing + Wproj transpose ----
  for (int u = b; u < 9248; u += NBLK) {
    if (u >= 8992) {  // Wproj transpose: 64x64 LDS tile, pad 65 (2-way = free)
      float (*tile)[65] = (float(*)[65])smem;
      int wli = u - 8992;
      const int h0 = (wli & 63) * 64;  // over 4096
      const int a0 = (wli >> 6) * 64;  // over 256
      const int r = tid >> 4;
      const int c = (tid & 15) * 4;
      __syncthreads();
#pragma unroll
      for (int p = 0; p < 4; ++p) {
        int row = p * 16 + r;
        float4 v = *(const float4*)(wp + (size_t)(h0 + row) * ADP + a0 + c);
        tile[c + 0][row] = v.x;
        tile[c + 1][row] = v.y;
        tile[c + 2][row] = v.z;
        tile[c + 3][row] = v.w;
      }
      __syncthreads();
#pragma unroll
      for (int q = 0; q < 2; ++q) {
        int idx = q * 256 + tid;
        int al = idx >> 3;             // a local 0..63
        int hg = (idx & 7) * 8;        // h local 0,8,..,56
        unsigned int w0 = (unsigned int)f2bf(tile[al][hg + 0]) |
                          ((unsigned int)f2bf(tile[al][hg + 1]) << 16);
        unsigned int w1 = (unsigned int)f2bf(tile[al][hg + 2]) |
                          ((unsigned int)f2bf(tile[al][hg + 3]) << 16);
        unsigned int w2 = (unsigned int)f2bf(tile[al][hg + 4]) |
                          ((unsigned int)f2bf(tile[al][hg + 5]) << 16);
        unsigned int w3 = (unsigned int)f2bf(tile[al][hg + 6]) |
                          ((unsigned int)f2bf(tile[al][hg + 7]) << 16);
        *(uint4*)(wpT + (size_t)(a0 + al) * HID + h0 + hg) =
            make_uint4(w0, w1, w2, w3);
      }
    } else if (u >= 8960) {  // routing: last active expert (-1 if none)
      int t = (u - 8960) * 256 + tid;
      const float* p = ew + (size_t)t * NEXP;
      int r = -1;
#pragma unroll
      for (int e = 0; e < NEXP; ++e)
        if (p[e] > 0.f) r = e;
      route[t] = r;
    } else {  // 2048-elem convert chunk
      const float* src; unsigned short* dst; int lb; bool strided = false;
      if      (u < 4096) { src = x;      dst = xb;  lb = u; }
      else if (u < 6144) { src = wup;    dst = wub; lb = u - 4096; }
      else if (u < 8192) { src = wout;   dst = wob; lb = u - 6144; strided = true; }
      else if (u < 8704) { src = wadapt; dst = wab; lb = u - 8192; }
      else               { src = wexp;   dst = web; lb = u - 8704; }
      size_t base = (size_t)lb * 2048;
#pragma unroll
      for (int h = 0; h < 2; ++h) {
        size_t off = base + (size_t)h * 1024 + (size_t)tid * 4;
        float4 v = *(const float4*)(src + off);
        ushort4 o;
        o.x = f2bf(v.x); o.y = f2bf(v.y); o.z = f2bf(v.z); o.w = f2bf(v.w);
        size_t doff = strided ? (off >> 12) * KAUG + (off & 4095) : off;
        *(ushort4*)(dst + doff) = o;
      }
    }
  }
  grid_bar(bar, NBLK);

  // ---- Phase B: H = silu(x @ Wup^T), 2048 tiles (gx=32, gy=64), 4/block ----
#pragma unroll 1
  for (int i = 0; i < 4; ++i) {
    int s = slot + i * 64;  // [0,256) per XCD
    gemm_body<0>(s & 31, xcd * 8 + (s >> 5), 0, xb, DEMB, wub, DEMB, Haug,
                 KAUG, nullptr, DEMB, 0, As, Bs);
  }
  grid_bar(bar, 2 * NBLK);

  // ---- Phase C: adapt split-K4 (512 tiles, 1/block)
  //              + Wcomb = Wout@Wproj split-K8 (128 tiles, blocks 0..127) ----
  {
    int z = b >> 7, rem = b & 127, bx, by;
    remap_xcd(rem, 2, 64, bx, by);
    gemm_body<1>(bx, by, z, Haug, KAUG, wab, HID, P, ADP, nullptr, HID / 4,
                 (long)TOK * ADP, As, Bs);
    if (b < 128) {
      int z2 = b >> 4, rem2 = b & 15, cx, cy;
      remap_xcd(rem2, 2, 8, cx, cy);
      gemm_body<1>(cx, cy, z2, wob, KAUG, wpT, HID, Pw, ADP, nullptr, HID / 8,
                   (long)DEMB * ADP, As, Bs);
    }
  }
  grid_bar(bar, 3 * NBLK);

  // ---- Phase D: reductions (P -> bf16 ab; Pw -> 0.1x bf16 wob tail) ----
  for (int u = b; u < 2304; u += NBLK) {
    if (u < 2048) {
      size_t i = ((size_t)u * 256 + tid) * 4;
      const size_t stride = (size_t)TOK * ADP;
      float4 p0 = *(const float4*)(P + i);
      float4 p1 = *(const float4*)(P + stride + i);
      float4 p2 = *(const float4*)(P + 2 * stride + i);
      float4 p3 = *(const float4*)(P + 3 * stride + i);
      ushort4 o;
      o.x = f2bf(p0.x + p1.x + p2.x + p3.x);
      o.y = f2bf(p0.y + p1.y + p2.y + p3.y);
      o.z = f2bf(p0.z + p1.z + p2.z + p3.z);
      o.w = f2bf(p0.w + p1.w + p2.w + p3.w);
      *(ushort4*)(ab + i) = o;
    } else {
      size_t i = ((size_t)(u - 2048) * 256 + tid) * 4;  // over 1024*256
      const size_t stride = (size_t)DEMB * ADP;
      float4 s = *(const float4*)(Pw + i);
#pragma unroll
      for (int k = 1; k < 8; ++k) {
        float4 p = *(const float4*)(Pw + k * stride + i);
        s.x += p.x; s.y += p.y; s.z += p.z; s.w += p.w;
      }
      size_t d = i >> 8, a = i & 255;
      ushort4 o;
      o.x = f2bf(0.1f * s.x); o.y = f2bf(0.1f * s.y);
      o.z = f2bf(0.1f * s.z); o.w = f2bf(0.1f * s.w);
      *(ushort4*)(wob + d * KAUG + HID + a) = o;
    }
  }
  grid_bar(bar, 4 * NBLK);

  // ---- Phase E: a_all = ab @ Wexp_all^T, keep winning slice -> asel (=P).
  //      1024 tiles (gx=16, gy=64), 2/block. P partials consumed in D. ----
#pragma unroll 1
  for (int i = 0; i < 2; ++i) {
    int s = slot + i * 64;  // [0,128) per XCD
    gemm_body<3>(s & 15, xcd * 8 + (s >> 4), 0, ab, ADP, web, ADP, P, ADP,
                 route, ADP, 0, As, Bs);
  }
  grid_bar(bar, 5 * NBLK);

  // ---- Phase F: LayerNorm per token (one wave per token) -> Haug tail ----
  for (int u = b; u < 2048; u += NBLK) {
    const int lane = tid & 63;
    const int t = u * 4 + (tid >> 6);
    const int e = route[t];
    float4 v = *(const float4*)(P + (size_t)t * ADP + lane * 4);  // asel
    float s1 = v.x + v.y + v.z + v.w;
    float s2 = v.x * v.x + v.y * v.y + v.z * v.z + v.w * v.w;
#pragma unroll
    for (int off = 32; off > 0; off >>= 1) {
      s1 += __shfl_down(s1, off);
      s2 += __shfl_down(s2, off);
    }
    s1 = __shfl(s1, 0);
    s2 = __shfl(s2, 0);
    float mu = s1 * (1.0f / ADP);
    float var = s2 * (1.0f / ADP) - mu * mu;
    float rstd = rsqrtf(var + 1e-5f);
    ushort4 o;
    if (e >= 0) {
      float4 g = *(const float4*)(gamma + (size_t)e * ADP + lane * 4);
      float4 bb = *(const float4*)(beta + (size_t)e * ADP + lane * 4);
      o.x = f2bf((v.x - mu) * rstd * g.x + bb.x);
      o.y = f2bf((v.y - mu) * rstd * g.y + bb.y);
      o.z = f2bf((v.z - mu) * rstd * g.z + bb.z);
      o.w = f2bf((v.w - mu) * rstd * g.w + bb.w);
    } else {
      o.x = o.y = o.z = o.w = 0;
    }
    *(ushort4*)(Haug + (size_t)t * KAUG + HID + lane * 4) = o;
  }
  grid_bar(bar, 6 * NBLK);

  // ---- Phase G: out = Haug @ [Wout|Wcomb]^T, K=4352, 512 tiles, 1/block ----
  gemm_body<1>(slot & 7, xcd * 8 + (slot >> 3), 0, Haug, KAUG, wob, KAUG, out,
               DEMB, nullptr, KAUG, 0, As, Bs);
}

// ---------------------------------------------------------------------------
extern "C" void kernel_launch(void* const* d_in, const int* in_sizes, int n_in,
                              void* d_out, int out_size, void* d_ws, size_t ws_size,
                              hipStream_t stream) {
  const float* x     = (const float*)d_in[0];
  const float* ew    = (const float*)d_in[1];
  const float* W_up  = (const float*)d_in[2];
  const float* W_ad  = (const float*)d_in[3];
  const float* W_ex  = (const float*)d_in[4];
  const float* gam   = (const float*)d_in[5];
  const float* bet   = (const float*)d_in[6];
  const float* W_pr  = (const float*)d_in[7];
  const float* W_out = (const float*)d_in[8];
  float* out = (float*)d_out;

  // workspace layout (~150 MiB total)
  char* ws = (char*)d_ws;
  size_t off = 0;
  auto alloc = [&](size_t n) {
    char* p = ws + off;
    off += (n + 255) & ~(size_t)255;
    return p;
  };
  int*          bar    = (int*)alloc(256);                                 // barrier counter
  unsigned short* xb   = (unsigned short*)alloc((size_t)TOK * DEMB * 2);
  unsigned short* wub  = (unsigned short*)alloc((size_t)HID * DEMB * 2);
  unsigned short* wob  = (unsigned short*)alloc((size_t)DEMB * KAUG * 2);  // [Wout | Wcomb]
  unsigned short* wab  = (unsigned short*)alloc((size_t)ADP * HID * 2);
  unsigned short* web  = (unsigned short*)alloc((size_t)NEXP * ADP * ADP * 2);
  unsigned short* wpT  = (unsigned short*)alloc((size_t)ADP * HID * 2);    // Wproj^T bf16
  unsigned short* Haug = (unsigned short*)alloc((size_t)TOK * KAUG * 2);   // [H | anorm]
  float*          P    = (float*)alloc((size_t)4 * TOK * ADP * 4);         // partials; asel aliases
  float*          Pw   = (float*)alloc((size_t)8 * DEMB * ADP * 4);
  unsigned short* ab   = (unsigned short*)alloc((size_t)TOK * ADP * 2);
  int*          route  = (int*)alloc((size_t)TOK * 4);

  hipMemsetAsync(bar, 0, 4, stream);
  fused_all<<<NBLK, 256, 0, stream>>>(x, ew, W_up, W_ad, W_ex, gam, bet, W_pr,
                                      W_out, xb, wub, wob, wab, web, wpT, Haug,
                                      P, Pw, ab, route, out, bar);
}